// Round 4
// baseline (379.310 us; speedup 1.0000x reference)
//
#include <hip/hip_runtime.h>
#include <hip/hip_bf16.h>

typedef float  f32x16 __attribute__((ext_vector_type(16)));
typedef float  f32x4v __attribute__((ext_vector_type(4)));
typedef short  bf16x8 __attribute__((ext_vector_type(8)));

#define NFRAG 36
#define FRG_BYTES (NFRAG * 64 * 16)        // 36864
#define W2T_BYTES 4096                     // 64 lanes x 16 f32
#define LDS_BYTES (FRG_BYTES + W2T_BYTES)  // 40960
#define WC_BYTE_OFF LDS_BYTES

#define BLK 256
#define COPY_BLOCKS 256
#define EDGE_BLOCKS 1024
#define GRID (COPY_BLOCKS + EDGE_BLOCKS)
#define EDGE_WAVES (EDGE_BLOCKS * 4)

__device__ __forceinline__ float sigf(float v) { return 1.0f / (1.0f + __expf(-v)); }
__device__ __forceinline__ float tanhf_fast(float v) {
    float a = fabsf(v);
    float t = __expf(-2.0f * a);
    float r = (1.0f - t) / (1.0f + t);
    return v < 0.0f ? -r : r;
}
__device__ __forceinline__ unsigned pk(float a, float b) {
    union { __hip_bfloat162 h; unsigned u; } c;
    c.h = __float22bfloat162_rn(make_float2(a, b));
    return c.u;
}

union FragU { uint4 u4; bf16x8 s8; unsigned u[4]; };

__device__ __forceinline__ f32x16 mfma32(bf16x8 a, bf16x8 b, f32x16 c) {
    return __builtin_amdgcn_mfma_f32_32x32x16_bf16(a, b, c, 0, 0, 0);
}

__device__ __forceinline__ void relayout32(f32x16 v, bool hlo, FragU& o0, FragU& o1) {
    unsigned p0 = pk(v[0], v[1]),   p1 = pk(v[2], v[3]);
    unsigned p2 = pk(v[4], v[5]),   p3 = pk(v[6], v[7]);
    unsigned p4 = pk(v[8], v[9]),   p5 = pk(v[10], v[11]);
    unsigned p6 = pk(v[12], v[13]), p7 = pk(v[14], v[15]);
    unsigned q0 = __shfl_xor(hlo ? p2 : p0, 32, 64);
    unsigned q1 = __shfl_xor(hlo ? p3 : p1, 32, 64);
    unsigned q2 = __shfl_xor(hlo ? p6 : p4, 32, 64);
    unsigned q3 = __shfl_xor(hlo ? p7 : p5, 32, 64);
    o0.u[0] = hlo ? p0 : q0; o0.u[1] = hlo ? p1 : q1;
    o0.u[2] = hlo ? q0 : p2; o0.u[3] = hlo ? q1 : p3;
    o1.u[0] = hlo ? p4 : q2; o1.u[1] = hlo ? p5 : q3;
    o1.u[2] = hlo ? q2 : p6; o1.u[3] = hlo ? q3 : p7;
}

__global__ void winner_k(const int* __restrict__ dst_ids, int* __restrict__ winner, int E) {
    int e = blockIdx.x * 256 + threadIdx.x;
    if (e < E) atomicMax(winner + dst_ids[e], e + 1);
}

__global__ void prep_k(const float* __restrict__ msg_W1, const float* __restrict__ msg_b1,
                       const float* __restrict__ msg_W2, const float* __restrict__ msg_b2,
                       const float* __restrict__ w_ih, const float* __restrict__ b_ih,
                       const float* __restrict__ w_hh, const float* __restrict__ b_hh,
                       const float* __restrict__ Wv, const float* __restrict__ bv,
                       const float* __restrict__ Wo, const float* __restrict__ bo,
                       const float* __restrict__ emb_W1, const float* __restrict__ emb_b1,
                       const float* __restrict__ emb_W2, const float* __restrict__ emb_b2,
                       const float* __restrict__ cls_W1, const float* __restrict__ cls_b1,
                       const float* __restrict__ cls_W2, float* __restrict__ WSf) {
    int t = threadIdx.x;  // one block, 256 threads
    unsigned short* frg = (unsigned short*)WSf;
    float* w2t = (float*)((char*)WSf + FRG_BYTES);
    float* WC  = (float*)((char*)WSf + WC_BYTE_OFF);
    float* bc  = WC + 1024;
    for (int i = t; i < 1024; i += 256) {
        int j = i >> 5, k = i & 31;
        float a = 0.0f;
        for (int o = 0; o < 32; ++o) a += Wo[j * 32 + o] * Wv[o * 32 + k];
        WC[i] = a;
    }
    if (t < 32) {
        float a = bo[t];
        for (int o = 0; o < 32; ++o) a += Wo[t * 32 + o] * bv[o];
        bc[t] = a;
    }
    for (int i = t; i < 1024; i += 256) {
        int l = i >> 4, r = i & 15;
        w2t[i] = cls_W2[(r & 3) + 8 * (r >> 2) + 4 * (l >> 5)];
    }
    __syncthreads();
    for (int idx = t; idx < NFRAG * 512; idx += 256) {
        int f = idx >> 9, l = (idx >> 3) & 63, i = idx & 7;
        int j = l & 31, h = l >> 5;
        int L, c;
        if      (f < 5)  { L = 0; c = f; }
        else if (f < 8)  { L = 1; c = f - 5; }
        else if (f < 13) { L = 2; c = f - 8; }
        else if (f < 18) { L = 3; c = f - 13; }
        else if (f < 21) { L = 4; c = f - 18; }
        else if (f < 24) { L = 5; c = f - 21; }
        else if (f < 27) { L = 6; c = f - 24; }
        else if (f < 30) { L = 7; c = f - 27; }
        else if (f < 33) { L = 8; c = f - 30; }
        else             { L = 9; c = f - 33; }
        int k = 16 * c + 8 * h + i;
        float v = 0.0f;
        switch (L) {
            case 0: v = (k < 67) ? msg_W1[j * 67 + k] : (k == 67 ? msg_b1[j] : 0.0f); break;
            case 1: v = (k < 32) ? msg_W2[j * 32 + k] : (k == 32 ? msg_b2[j] : 0.0f); break;
            case 2: { int jj = 32 + j;
                      v = (k < 32) ? w_ih[jj * 32 + k] : (k < 64) ? w_hh[jj * 32 + k - 32]
                          : (k == 64) ? b_ih[jj] + b_hh[jj] : 0.0f; } break;
            case 3: { int jj = j;
                      v = (k < 32) ? w_ih[jj * 32 + k] : (k < 64) ? w_hh[jj * 32 + k - 32]
                          : (k == 64) ? b_ih[jj] + b_hh[jj] : 0.0f; } break;
            case 4: { int jj = 64 + j;
                      v = (k < 32) ? w_hh[jj * 32 + k] : (k == 32 ? b_hh[jj] : 0.0f); } break;
            case 5: { int jj = 64 + j;
                      v = (k < 32) ? w_ih[jj * 32 + k] : (k == 32 ? b_ih[jj] : 0.0f); } break;
            case 6: v = (k < 32) ? WC[j * 32 + k] : (k == 32 ? bc[j] : 0.0f); break;
            case 7: v = (k < 34) ? emb_W1[j * 34 + k] : (k == 34 ? emb_b1[j] : 0.0f); break;
            case 8: v = (k < 32) ? emb_W2[j * 32 + k] : (k == 32 ? emb_b2[j] : 0.0f); break;
            default: v = (k < 32) ? cls_W1[j * 32 + k] : (k == 32 ? cls_b1[j] : 0.0f); break;
        }
        __hip_bfloat16 hv = __float2bfloat16(v);
        frg[idx] = *(unsigned short*)&hv;
    }
}

__global__ __launch_bounds__(BLK, 3) void tgn_mfma32(
    const int* __restrict__ src_ids, const int* __restrict__ dst_ids,
    const float* __restrict__ edge_feat, const float* __restrict__ delta_t,
    const float* __restrict__ memory, const float* __restrict__ cls_b2,
    const float* __restrict__ WSf, const int* __restrict__ winner,
    float* __restrict__ probs, float* __restrict__ out_mem,
    int E, int N, int ngrp) {
    __shared__ uint4 sbuf[LDS_BYTES / 16];
    int bid = blockIdx.x, tid = threadIdx.x;

    if (bid < COPY_BLOCKS) {  // copy workers: non-winner rows -> out_mem
        const float4* m4 = (const float4*)memory;
        float4* o4 = (float4*)out_mem;
        long total4 = (long)N * 8;
        for (long i = (long)bid * BLK + tid; i < total4; i += (long)COPY_BLOCKS * BLK) {
            int row = (int)(i >> 3);
            if (winner[row] == 0) o4[i] = m4[i];
        }
        return;
    }

    {
        const uint4* s = (const uint4*)WSf;
        for (int i = tid; i < LDS_BYTES / 16; i += BLK) sbuf[i] = s[i];
    }
    __syncthreads();
    const unsigned short* frg = (const unsigned short*)sbuf;
    const float* w2t = (const float*)((const char*)sbuf + FRG_BYTES);

    int wv = tid >> 6, lane = tid & 63;
    int eI = lane & 31, h = lane >> 5;
    bool hlo = (h == 0);
    int ewid = (bid - COPY_BLOCKS) * 4 + wv;
    float clsb2 = cls_b2[0];

    for (int grp = ewid; grp < ngrp; grp += EDGE_WAVES) {
        int e = grp * 32 + eI; if (e >= E) e = E - 1;
        int ob = 0;
        asm volatile("" : "+v"(ob));  // keep LDS reads inside the loop
        int src = src_ids[e], dst = dst_ids[e];
        float2 ef = ((const float2*)edge_feat)[e];
        float dtv = delta_t[e];
        bool win = (winner[dst] == e + 1);

#define LF(f) (*(const FragU*)(frg + (((f) * 64 + lane) * 8 + ob))).s8

        const float4* sp = (const float4*)(memory + (size_t)src * 32);
        const float4* dp = (const float4*)(memory + (size_t)dst * 32);
        float4 sA = sp[2 * h], sB = sp[2 * h + 1], sC = sp[4 + 2 * h], sD = sp[5 + 2 * h];
        float4 dA = dp[2 * h], dB = dp[2 * h + 1], dC = dp[4 + 2 * h], dD = dp[5 + 2 * h];
        FragU Bs0, Bs1, Bd0, Bd1;
        Bs0.u[0] = pk(sA.x, sA.y); Bs0.u[1] = pk(sA.z, sA.w);
        Bs0.u[2] = pk(sB.x, sB.y); Bs0.u[3] = pk(sB.z, sB.w);
        Bs1.u[0] = pk(sC.x, sC.y); Bs1.u[1] = pk(sC.z, sC.w);
        Bs1.u[2] = pk(sD.x, sD.y); Bs1.u[3] = pk(sD.z, sD.w);
        Bd0.u[0] = pk(dA.x, dA.y); Bd0.u[1] = pk(dA.z, dA.w);
        Bd0.u[2] = pk(dB.x, dB.y); Bd0.u[3] = pk(dB.z, dB.w);
        Bd1.u[0] = pk(dC.x, dC.y); Bd1.u[1] = pk(dC.z, dC.w);
        Bd1.u[2] = pk(dD.x, dD.y); Bd1.u[3] = pk(dD.z, dD.w);
        f32x16 dmt;
        {
            float4 t0 = dp[h], t1 = dp[2 + h], t2 = dp[4 + h], t3 = dp[6 + h];
            dmt[0]=t0.x; dmt[1]=t0.y; dmt[2]=t0.z; dmt[3]=t0.w;
            dmt[4]=t1.x; dmt[5]=t1.y; dmt[6]=t1.z; dmt[7]=t1.w;
            dmt[8]=t2.x; dmt[9]=t2.y; dmt[10]=t2.z; dmt[11]=t2.w;
            dmt[12]=t3.x; dmt[13]=t3.y; dmt[14]=t3.z; dmt[15]=t3.w;
        }
        FragU Bbias, Bt1, Bt2;
        Bbias.u[0] = hlo ? 0x00003F80u : 0u; Bbias.u[1] = 0; Bbias.u[2] = 0; Bbias.u[3] = 0;
        Bt1.u[0] = hlo ? pk(ef.x, ef.y) : 0u; Bt1.u[1] = hlo ? pk(dtv, 1.0f) : 0u;
        Bt1.u[2] = 0; Bt1.u[3] = 0;
        Bt2.u[0] = hlo ? pk(ef.x, ef.y) : 0u; Bt2.u[1] = hlo ? pk(1.0f, 0.0f) : 0u;
        Bt2.u[2] = 0; Bt2.u[3] = 0;

        // msg1
        f32x16 c{};
        c = mfma32(LF(0), Bs0.s8, c); c = mfma32(LF(1), Bs1.s8, c);
        c = mfma32(LF(2), Bd0.s8, c); c = mfma32(LF(3), Bd1.s8, c);
        c = mfma32(LF(4), Bt1.s8, c);
#pragma unroll
        for (int r = 0; r < 16; ++r) c[r] = fmaxf(c[r], 0.0f);
        FragU Bh0, Bh1; relayout32(c, hlo, Bh0, Bh1);

        // msg2
        f32x16 cm{};
        cm = mfma32(LF(5), Bh0.s8, cm); cm = mfma32(LF(6), Bh1.s8, cm);
        cm = mfma32(LF(7), Bbias.s8, cm);
        FragU Bm0, Bm1; relayout32(cm, hlo, Bm0, Bm1);

        // attn -> emb1 -> emb2 -> cls
        f32x16 ca{};
        ca = mfma32(LF(24), Bd0.s8, ca); ca = mfma32(LF(25), Bd1.s8, ca);
        ca = mfma32(LF(26), Bbias.s8, ca);
        FragU Ba0, Ba1; relayout32(ca, hlo, Ba0, Ba1);
        f32x16 ce{};
        ce = mfma32(LF(27), Ba0.s8, ce); ce = mfma32(LF(28), Ba1.s8, ce);
        ce = mfma32(LF(29), Bt2.s8, ce);
#pragma unroll
        for (int r = 0; r < 16; ++r) ce[r] = fmaxf(ce[r], 0.0f);
        FragU B10, B11; relayout32(ce, hlo, B10, B11);
        f32x16 c2{};
        c2 = mfma32(LF(30), B10.s8, c2); c2 = mfma32(LF(31), B11.s8, c2);
        c2 = mfma32(LF(32), Bbias.s8, c2);
        FragU B20, B21; relayout32(c2, hlo, B20, B21);
        f32x16 cc{};
        cc = mfma32(LF(33), B20.s8, cc); cc = mfma32(LF(34), B21.s8, cc);
        cc = mfma32(LF(35), Bbias.s8, cc);
        float part = 0.0f;
        {
            const f32x4v* wp = (const f32x4v*)(w2t + (lane * 16 + ob));
#pragma unroll
            for (int q = 0; q < 4; ++q) {
                f32x4v w = wp[q];
#pragma unroll
                for (int i = 0; i < 4; ++i)
                    part = fmaf(fmaxf(cc[4 * q + i], 0.0f), w[i], part);
            }
        }
        part += __shfl_xor(part, 32, 64);
        if (hlo) {
            int ee = grp * 32 + eI;
            if (ee < E) probs[ee] = sigf(part + clsb2);
        }

        // GRU
        f32x16 cr{};
        cr = mfma32(LF(13), Bm0.s8, cr); cr = mfma32(LF(14), Bm1.s8, cr);
        cr = mfma32(LF(15), Bd0.s8, cr); cr = mfma32(LF(16), Bd1.s8, cr);
        cr = mfma32(LF(17), Bbias.s8, cr);
        f32x16 ch{};
        ch = mfma32(LF(18), Bd0.s8, ch); ch = mfma32(LF(19), Bd1.s8, ch);
        ch = mfma32(LF(20), Bbias.s8, ch);
        f32x16 cn;
#pragma unroll
        for (int r = 0; r < 16; ++r) cn[r] = sigf(cr[r]) * ch[r];
        cn = mfma32(LF(21), Bm0.s8, cn); cn = mfma32(LF(22), Bm1.s8, cn);
        cn = mfma32(LF(23), Bbias.s8, cn);
        f32x16 cz{};
        cz = mfma32(LF(8), Bm0.s8, cz);  cz = mfma32(LF(9), Bm1.s8, cz);
        cz = mfma32(LF(10), Bd0.s8, cz); cz = mfma32(LF(11), Bd1.s8, cz);
        cz = mfma32(LF(12), Bbias.s8, cz);
        f32x16 uu;
#pragma unroll
        for (int r = 0; r < 16; ++r) {
            float n = tanhf_fast(cn[r]);
            float z = sigf(cz[r]);
            uu[r] = n + z * (dmt[r] - n);
        }
        if (win) {
            float4* orow = (float4*)(out_mem + (size_t)dst * 32);
            orow[h]     = make_float4(uu[0],  uu[1],  uu[2],  uu[3]);
            orow[2 + h] = make_float4(uu[4],  uu[5],  uu[6],  uu[7]);
            orow[4 + h] = make_float4(uu[8],  uu[9],  uu[10], uu[11]);
            orow[6 + h] = make_float4(uu[12], uu[13], uu[14], uu[15]);
        }
#undef LF
    }
}

extern "C" void kernel_launch(void* const* d_in, const int* in_sizes, int n_in,
                              void* d_out, int out_size, void* d_ws, size_t ws_size,
                              hipStream_t stream) {
    const int*   src_ids   = (const int*)d_in[0];
    const int*   dst_ids   = (const int*)d_in[1];
    const float* edge_feat = (const float*)d_in[2];
    const float* delta_t   = (const float*)d_in[3];
    const float* memory    = (const float*)d_in[4];
    const float* msg_W1 = (const float*)d_in[5],  *msg_b1 = (const float*)d_in[6];
    const float* msg_W2 = (const float*)d_in[7],  *msg_b2 = (const float*)d_in[8];
    const float* w_ih   = (const float*)d_in[9],  *b_ih   = (const float*)d_in[10];
    const float* w_hh   = (const float*)d_in[11], *b_hh   = (const float*)d_in[12];
    const float* Wv     = (const float*)d_in[13], *bv     = (const float*)d_in[14];
    const float* Wo     = (const float*)d_in[15], *bo     = (const float*)d_in[16];
    const float* emb_W1 = (const float*)d_in[17], *emb_b1 = (const float*)d_in[18];
    const float* emb_W2 = (const float*)d_in[19], *emb_b2 = (const float*)d_in[20];
    const float* cls_W1 = (const float*)d_in[21], *cls_b1 = (const float*)d_in[22];
    const float* cls_W2 = (const float*)d_in[23], *cls_b2 = (const float*)d_in[24];

    int E = in_sizes[0];
    int N = in_sizes[4] / 32;
    int ngrp = (E + 31) / 32;

    int*   winner = (int*)d_ws;
    float* WSf    = (float*)((char*)d_ws + (size_t)N * sizeof(int));
    float* probs  = (float*)d_out;
    float* outmem = probs + E;

    hipMemsetAsync(winner, 0, (size_t)N * sizeof(int), stream);
    winner_k<<<(E + 255) / 256, 256, 0, stream>>>(dst_ids, winner, E);
    prep_k<<<1, 256, 0, stream>>>(msg_W1, msg_b1, msg_W2, msg_b2,
                                  w_ih, b_ih, w_hh, b_hh,
                                  Wv, bv, Wo, bo,
                                  emb_W1, emb_b1, emb_W2, emb_b2,
                                  cls_W1, cls_b1, cls_W2, WSf);
    tgn_mfma32<<<GRID, BLK, 0, stream>>>(src_ids, dst_ids, edge_feat, delta_t,
                                         memory, cls_b2, WSf, winner,
                                         probs, outmem, E, N, ngrp);
}